// Round 16
// baseline (558.107 us; speedup 1.0000x reference)
//
#include <hip/hip_runtime.h>
#include <hip/hip_bf16.h>

typedef unsigned short u16;
typedef __attribute__((ext_vector_type(8))) short short8;
typedef __attribute__((ext_vector_type(4))) short short4s;
typedef __attribute__((ext_vector_type(4))) float f32x4;

__device__ __forceinline__ u16 f2b(float f) {
  union { float f; unsigned u; } c; c.f = f;
  unsigned u = c.u;
  unsigned r = (u + 0x7FFFu + ((u >> 16) & 1u)) >> 16;
  return (u16)r;
}
__device__ __forceinline__ float b2f(u16 h) {
  union { unsigned u; float f; } c; c.u = ((unsigned)h) << 16;
  return c.f;
}

__device__ __forceinline__ void gload16(const u16* g, u16* l) {
  __builtin_amdgcn_global_load_lds((const __attribute__((address_space(1))) void*)g,
                                   (__attribute__((address_space(3))) void*)l, 16, 0, 0);
}

__device__ __forceinline__ short4s tr16(const u16* p) {
  short4s d;
  asm volatile("ds_read_b64_tr_b16 %0, %1"
               : "=v"(d)
               : "v"((const __attribute__((address_space(3))) u16*)p));
  return d;
}

#define MFMA(a, b, c) __builtin_amdgcn_mfma_f32_16x16x32_bf16(a, b, c, 0, 0, 0)

// ---------------- fused cast fp32 -> bf16 (x, wq, wk, wv, wo) -------------
__global__ __launch_bounds__(256) void cast_all(const float* __restrict__ x,
                                                const float* __restrict__ wq,
                                                const float* __restrict__ wk,
                                                const float* __restrict__ wv,
                                                const float* __restrict__ wo,
                                                u16* __restrict__ xb,
                                                u16* __restrict__ wqkv,
                                                u16* __restrict__ wob) {
  int i = blockIdx.x * 256 + threadIdx.x;
  const float4* s; u16* d; int off;
  if (i < 2097152)      { s = (const float4*)x;  d = xb;            off = i; }
  else if (i < 3145728) { s = (const float4*)wq; d = wqkv;          off = i - 2097152; }
  else if (i < 4194304) { s = (const float4*)wk; d = wqkv + 4194304; off = i - 3145728; }
  else if (i < 5242880) { s = (const float4*)wv; d = wqkv + 8388608; off = i - 4194304; }
  else                  { s = (const float4*)wo; d = wob;           off = i - 5242880; }
  float4 v = s[off];
  ushort4 r;
  r.x = f2b(v.x); r.y = f2b(v.y); r.z = f2b(v.z); r.w = f2b(v.w);
  *(ushort4*)(d + (size_t)off * 4) = r;
}

// ---------------- RoPE in-place on K region only (cols 2048..4095) --------
__global__ __launch_bounds__(256) void rope_k(u16* __restrict__ qkv,
                                              const float* __restrict__ fc,
                                              const float* __restrict__ fs) {
  int idx = blockIdx.x * 256 + threadIdx.x;
  int m = idx >> 8;
  int c = idx & 255;
  int s = m & 2047;
  int i0 = (c * 4) & 63;
  u16* p = qkv + (size_t)m * 6144 + 2048 + c * 8;
  short8 v = *(short8*)p;
  float4 cs = *(const float4*)(fc + (size_t)s * 64 + i0);
  float4 sn = *(const float4*)(fs + (size_t)s * 64 + i0);
  float cc[4] = {cs.x, cs.y, cs.z, cs.w};
  float ss[4] = {sn.x, sn.y, sn.z, sn.w};
#pragma unroll
  for (int t = 0; t < 4; ++t) {
    float x0 = b2f((u16)v[2 * t]);
    float x1 = b2f((u16)v[2 * t + 1]);
    float o0 = x0 * cc[t] - x1 * ss[t];
    float o1 = x0 * ss[t] + x1 * cc[t];
    v[2 * t]     = (short)f2b(o0);
    v[2 * t + 1] = (short)f2b(o1);
  }
  *(short8*)p = v;
}

// ---------------- 256x384 bf16 NT GEMM, BK=32 (unchanged R13) -------------
template <int F32OUT>
__global__ __launch_bounds__(512, 2) void gemm_wide(const u16* __restrict__ Ag,
                                                    const u16* __restrict__ Bg,
                                                    void* __restrict__ Cp,
                                                    int M, int N, int K) {
  __shared__ __align__(16) u16 lds[40960];
  const int tid = threadIdx.x;
  const int l = tid & 63, w = tid >> 6;
  const int wm = w >> 2, wn = w & 3;
  const int ln = l & 15, lk = l >> 4;
  const int nbn = N / 384;
  const int nwg = (M >> 8) * nbn;
  const int wg = ((blockIdx.x & 7) * (nwg >> 3)) + (blockIdx.x >> 3);
  const int row0 = (wg / nbn) << 8;
  const int col0 = (wg % nbn) * 384;
  const int T = K >> 5;

#define STAGE_A(t)                                                                     \
  {                                                                                    \
    _Pragma("unroll")                                                                  \
    for (int u = 0; u < 2; ++u) {                                                      \
      int e = u * 512 + tid;                                                           \
      int rr = e >> 2;                                                                 \
      gload16(Ag + (size_t)(row0 + rr) * K + (t) * 32 +                                \
                  (((e & 3) ^ ((rr >> 1) & 3)) << 3),                                  \
              lds + ((t) & 1) * 8192 + e * 8);                                         \
    }                                                                                  \
  }
#define STAGE_B(t)                                                                     \
  {                                                                                    \
    _Pragma("unroll")                                                                  \
    for (int u = 0; u < 3; ++u) {                                                      \
      int e = u * 512 + tid;                                                           \
      int rr = e >> 2;                                                                 \
      gload16(Bg + (size_t)(col0 + rr) * K + (t) * 32 +                                \
                  (((e & 3) ^ ((rr >> 1) & 3)) << 3),                                  \
              lds + 16384 + ((t) & 1) * 12288 + e * 8);                                \
    }                                                                                  \
  }

  f32x4 acc[8][6];
#pragma unroll
  for (int m = 0; m < 8; ++m)
#pragma unroll
    for (int n = 0; n < 6; ++n) acc[m][n] = (f32x4){0.f, 0.f, 0.f, 0.f};

  const int cx = (lk ^ ((ln >> 1) & 3)) << 3;

  STAGE_B(0); STAGE_A(0); STAGE_B(1);
  asm volatile("s_waitcnt vmcnt(3)" ::: "memory");
  __builtin_amdgcn_s_barrier();

  for (int t = 0; t < T; ++t) {
    const u16* aB = lds + (t & 1) * 8192;
    const u16* bB = lds + 16384 + (t & 1) * 12288;
    short8 bf[6];
    short8 af[4];

#pragma unroll
    for (int n = 0; n < 6; ++n)
      bf[n] = *(const short8*)&bB[(wn * 96 + n * 16 + ln) * 32 + cx];
#pragma unroll
    for (int mf = 0; mf < 4; ++mf)
      af[mf] = *(const short8*)&aB[(wm * 128 + mf * 16 + ln) * 32 + cx];
    if (t + 1 < T) STAGE_A(t + 1);
    __builtin_amdgcn_s_setprio(1);
#pragma unroll
    for (int mf = 0; mf < 4; ++mf)
#pragma unroll
      for (int n = 0; n < 6; ++n)
        acc[mf][n] = MFMA(af[mf], bf[n], acc[mf][n]);
    __builtin_amdgcn_s_setprio(0);
    __builtin_amdgcn_s_barrier();

#pragma unroll
    for (int mf = 0; mf < 4; ++mf)
      af[mf] = *(const short8*)&aB[(wm * 128 + (4 + mf) * 16 + ln) * 32 + cx];
    if (t + 2 < T) STAGE_B(t + 2);
    __builtin_amdgcn_s_setprio(1);
#pragma unroll
    for (int mf = 0; mf < 4; ++mf)
#pragma unroll
      for (int n = 0; n < 6; ++n)
        acc[4 + mf][n] = MFMA(af[mf], bf[n], acc[4 + mf][n]);
    __builtin_amdgcn_s_setprio(0);
    if (t + 2 < T) { asm volatile("s_waitcnt vmcnt(3)" ::: "memory"); }
    else           { asm volatile("s_waitcnt vmcnt(0)" ::: "memory"); }
    __builtin_amdgcn_s_barrier();
  }

#pragma unroll
  for (int m = 0; m < 8; ++m) {
    int r0 = row0 + wm * 128 + m * 16 + lk * 4;
#pragma unroll
    for (int n = 0; n < 6; ++n) {
      int cc = col0 + wn * 96 + n * 16 + ln;
#pragma unroll
      for (int j = 0; j < 4; ++j) {
        float v = acc[m][n][j];
        if (F32OUT) ((float*)Cp)[(size_t)(r0 + j) * N + cc] = v;
        else        ((u16*)Cp)[(size_t)(r0 + j) * N + cc]   = f2b(v);
      }
    }
  }
#undef STAGE_A
#undef STAGE_B
}

// ---------------- 256 x 128 NT GEMM (gemm2, unchanged gemm_big<2>) --------
template <int NREP, int F32OUT>
__global__ __launch_bounds__(512, 2) void gemm_big(const u16* __restrict__ Ag,
                                                   const u16* __restrict__ Bg,
                                                   void* __restrict__ Cp,
                                                   int M, int N, int K) {
  __shared__ __align__(16) u16 lds[32768 + NREP * 8192];
  const int tid = threadIdx.x;
  const int l = tid & 63, w = tid >> 6;
  const int wm = w >> 2, wn = w & 3;
  const int ln = l & 15, lk = l >> 4;
  const int BN = NREP * 64;
  const int nbn = N / BN;
  const int nwg = (M >> 8) * nbn;
  const int wg = ((blockIdx.x & 7) * (nwg >> 3)) + (blockIdx.x >> 3);
  const int row0 = (wg / nbn) << 8;
  const int col0 = (wg % nbn) * BN;
  const int T = K >> 6;

#define STAGE_A(t, h)                                                                  \
  {                                                                                    \
    _Pragma("unroll")                                                                  \
    for (int u = 0; u < 2; ++u) {                                                      \
      int e = u * 512 + tid;                                                           \
      int rr = (h) * 128 + (e >> 3);                                                   \
      gload16(Ag + (size_t)(row0 + rr) * K + (t) * 64 + (((e & 7) ^ (rr & 7)) << 3),   \
              lds + ((t) & 1) * 16384 + (h) * 8192 + e * 8);                           \
    }                                                                                  \
  }
#define STAGE_B(t, pb)                                                                 \
  {                                                                                    \
    int rr = (pb) * 64 + (tid >> 3);                                                   \
    gload16(Bg + (size_t)(col0 + rr) * K + (t) * 64 + (((tid & 7) ^ (rr & 7)) << 3),   \
            lds + 32768 + ((t) & 1) * NREP * 4096 + (pb) * 4096 + tid * 8);            \
  }

  f32x4 acc[8][NREP];
#pragma unroll
  for (int m = 0; m < 8; ++m)
#pragma unroll
    for (int n = 0; n < NREP; ++n) acc[m][n] = (f32x4){0.f, 0.f, 0.f, 0.f};

  const int x = ln & 7;
  const int c0 = (lk ^ x) << 3;
  const int c1 = ((4 + lk) ^ x) << 3;

#pragma unroll
  for (int pb = 0; pb < NREP; ++pb) STAGE_B(0, pb);
  STAGE_A(0, 0); STAGE_A(0, 1);
#pragma unroll
  for (int pb = 0; pb < NREP; ++pb) STAGE_B(1, pb);
  asm volatile("s_waitcnt vmcnt(2)" ::: "memory");
  __builtin_amdgcn_s_barrier();

  for (int t = 0; t < T; ++t) {
    const u16* aB = lds + (t & 1) * 16384 + wm * 8192;
    const u16* bB = lds + 32768 + (t & 1) * NREP * 4096;
    short8 bf[NREP][2];
#pragma unroll
    for (int p = 0; p < 4; ++p) {
      if (p == 0) {
#pragma unroll
        for (int n = 0; n < NREP; ++n) {
          int rb = (wn * NREP * 16 + n * 16 + ln) * 64;
          bf[n][0] = *(const short8*)&bB[rb + c0];
          bf[n][1] = *(const short8*)&bB[rb + c1];
        }
      }
      short8 af[2][2];
#pragma unroll
      for (int m2 = 0; m2 < 2; ++m2) {
        int ra = ((p * 2 + m2) * 16 + ln) * 64;
        af[m2][0] = *(const short8*)&aB[ra + c0];
        af[m2][1] = *(const short8*)&aB[ra + c1];
      }
      if (p == 0)      { if (t + 1 < T) STAGE_A(t + 1, 0); }
      else if (p == 1) { if (t + 1 < T) STAGE_A(t + 1, 1);
                         if (t + 2 < T) STAGE_B(t + 2, 0); }
      else if (p == 2) { if (t + 2 < T) STAGE_B(t + 2, 1); }

      __builtin_amdgcn_s_setprio(1);
#pragma unroll
      for (int m2 = 0; m2 < 2; ++m2)
#pragma unroll
        for (int n = 0; n < NREP; ++n)
#pragma unroll
          for (int kk = 0; kk < 2; ++kk)
            acc[p * 2 + m2][n] = MFMA(af[m2][kk], bf[n][kk], acc[p * 2 + m2][n]);
      __builtin_amdgcn_s_setprio(0);

      if (p == 3) {
        if (t + 2 < T)      { asm volatile("s_waitcnt vmcnt(2)" ::: "memory"); }
        else if (t + 1 < T) { asm volatile("s_waitcnt vmcnt(0)" ::: "memory"); }
      }
      __builtin_amdgcn_s_barrier();
    }
  }

#pragma unroll
  for (int m = 0; m < 8; ++m) {
    int r0 = row0 + wm * 128 + m * 16 + lk * 4;
#pragma unroll
    for (int n = 0; n < NREP; ++n) {
      int cc = col0 + wn * NREP * 16 + n * 16 + ln;
#pragma unroll
      for (int j = 0; j < 4; ++j) {
        float v = acc[m][n][j];
        if (F32OUT) ((float*)Cp)[(size_t)(r0 + j) * N + cc] = v;
        else        ((u16*)Cp)[(size_t)(r0 + j) * N + cc]   = f2b(v);
      }
    }
  }
#undef STAGE_A
#undef STAGE_B
}

// ---------------- flash attention: causal, hd=128, H=16 ----------------
// R16: single-buffered K AND V (LDS 50 KB -> 3 blocks/CU), counted vmcnt
// (never drain the in-flight prefetch). Per-thread load FIFO per tile:
// [V(t)x2, K(t+1)x2, V(t+1)x2]. Before PV: vmcnt(2) drains V(t) (last
// tile: vmcnt(0)); after staging V(t+1): vmcnt(2) drains K(t+1). Four raw
// barriers/tile: post-QK (K overwrite safe), post-V-drain (all lanes'
// V landed), post-PV (V overwrite safe), post-K-drain (all lanes' K landed).
// Balanced 512-block split as R15.
__global__ __launch_bounds__(512, 6) void attn_fwd(const u16* __restrict__ qkv,
                                                   const float* __restrict__ fc,
                                                   const float* __restrict__ fs,
                                                   u16* __restrict__ out) {
  __shared__ __align__(16) u16 sK[64 * 128];
  __shared__ __align__(16) u16 sV[64 * 128];
  __shared__ __align__(16) u16 sP[8][16 * 72];
  const int tid = threadIdx.x, l = tid & 63, w = tid >> 6;   // w 0..7
  const int ln = l & 15, lk = l >> 4;

  const int bid = blockIdx.x;                 // 512 blocks
  const int idx = bid & 255, half = bid >> 8;
  const int l0 = ((idx & 7) << 5) | (idx >> 3);   // XCD-cluster (0..255)
  const int bh = l0 >> 3, pr = l0 & 7;
  const int qt = half ? pr : (15 - pr);       // big tiles in first 256 bids
  const int b = bh >> 4, h = bh & 15;

  const u16* Kp = qkv + (size_t)b * 2048 * 6144 + 2048 + h * 128;
  const u16* Vp = Kp + 2048;
  const float scale = 0.08838834764831845f;

  const int m0 = b * 2048 + qt * 128;
  const u16* Qp = qkv + (size_t)m0 * 6144 + h * 128;
  const int srow = qt * 128 + w * 16 + ln;

  short8 qf[4];
#pragma unroll
  for (int kc = 0; kc < 4; ++kc) {
    short8 raw = *(const short8*)(Qp + (size_t)(w * 16 + ln) * 6144 + kc * 32 + lk * 8);
    float4 c4 = *(const float4*)(fc + (size_t)srow * 64 + kc * 16 + lk * 4);
    float4 s4 = *(const float4*)(fs + (size_t)srow * 64 + kc * 16 + lk * 4);
    float cc[4] = {c4.x * scale, c4.y * scale, c4.z * scale, c4.w * scale};
    float ss[4] = {s4.x * scale, s4.y * scale, s4.z * scale, s4.w * scale};
#pragma unroll
    for (int t = 0; t < 4; ++t) {
      float x0 = b2f((u16)raw[2 * t]);
      float x1 = b2f((u16)raw[2 * t + 1]);
      qf[kc][2 * t]     = (short)f2b(x0 * cc[t] - x1 * ss[t]);
      qf[kc][2 * t + 1] = (short)f2b(x0 * ss[t] + x1 * cc[t]);
    }
  }

  f32x4 o[8];
#pragma unroll
  for (int d = 0; d < 8; ++d) o[d] = (f32x4){0.f, 0.f, 0.f, 0.f};
  float mrow[4] = {-1e9f, -1e9f, -1e9f, -1e9f};
  float lsum[4] = {0.f, 0.f, 0.f, 0.f};

  const int ntl = 2 * qt + 2;

  // prologue: K(0) -> sK, V(0) -> sV; syncthreads drains everything
  {
#pragma unroll
    for (int q = 0; q < 2; ++q) {
      int e = q * 512 + tid;
      int r = e >> 4, p = e & 15;
      gload16(Kp + (size_t)r * 6144 + ((p ^ (r & 7)) << 3), &sK[e * 8]);
      int j = ((e >> 6) << 2) + ((e & 7) >> 1);
      int d = (((e >> 3) & 7) << 4) + ((e & 1) << 3);
      gload16(Vp + (size_t)j * 6144 + d, &sV[e * 8]);
    }
  }
  __syncthreads();

  for (int jt = 0; jt < ntl; ++jt) {
    // ---- QK^T from sK (K(jt) landed) ----
    f32x4 sf[4];
    __builtin_amdgcn_s_setprio(1);
#pragma unroll
    for (int nc = 0; nc < 4; ++nc) {
      f32x4 s = (f32x4){0.f, 0.f, 0.f, 0.f};
#pragma unroll
      for (int kc = 0; kc < 4; ++kc) {
        int r = nc * 16 + ln;
        short8 kb = *(const short8*)&sK[r * 128 + (((kc << 2) + lk) ^ (r & 7)) * 8];
        s = MFMA(qf[kc], kb, s);
      }
      sf[nc] = s;
    }
    __builtin_amdgcn_s_setprio(0);

    // BAR_A: all waves done reading K(jt) -> safe to overwrite sK
    __builtin_amdgcn_sched_barrier(0);
    __builtin_amdgcn_s_barrier();
    __builtin_amdgcn_sched_barrier(0);
    if (jt + 1 < ntl) {
      const u16* Kt = Kp + (size_t)(jt + 1) * 64 * 6144;
#pragma unroll
      for (int q = 0; q < 2; ++q) {
        int e = q * 512 + tid;
        int r = e >> 4, p = e & 15;
        gload16(Kt + (size_t)r * 6144 + ((p ^ (r & 7)) << 3), &sK[e * 8]);
      }
    }

    // causal mask on diagonal-crossing tiles
    if (jt >= 2 * qt) {
      int ig = qt * 128 + w * 16 + lk * 4;
#pragma unroll
      for (int nc = 0; nc < 4; ++nc) {
        int jg = jt * 64 + nc * 16 + ln;
#pragma unroll
        for (int j = 0; j < 4; ++j)
          sf[nc][j] = (jg > ig + j) ? -1e9f : sf[nc][j];
      }
    }

    // ---- defer-max ----
    float tm[4];
#pragma unroll
    for (int j = 0; j < 4; ++j)
      tm[j] = fmaxf(fmaxf(sf[0][j], sf[1][j]), fmaxf(sf[2][j], sf[3][j]));
    int ok = (tm[0] <= mrow[0] + 8.f) & (tm[1] <= mrow[1] + 8.f) &
             (tm[2] <= mrow[2] + 8.f) & (tm[3] <= mrow[3] + 8.f);
    if (!__all(ok)) {
#pragma unroll
      for (int off = 1; off < 16; off <<= 1)
#pragma unroll
        for (int j = 0; j < 4; ++j) tm[j] = fmaxf(tm[j], __shfl_xor(tm[j], off, 16));
      float al[4];
#pragma unroll
      for (int j = 0; j < 4; ++j) {
        float nm = fmaxf(mrow[j], tm[j]);
        al[j] = __expf(mrow[j] - nm);
        mrow[j] = nm;
      }
#pragma unroll
      for (int d = 0; d < 8; ++d)
#pragma unroll
        for (int j = 0; j < 4; ++j) o[d][j] *= al[j];
#pragma unroll
      for (int j = 0; j < 4; ++j) lsum[j] *= al[j];
    }

    // ---- P = exp(S - m): compiler bf16 cast; lsum from unrounded p ----
#pragma unroll
    for (int nc = 0; nc < 4; ++nc)
#pragma unroll
      for (int j = 0; j < 4; ++j) {
        float p = __expf(sf[nc][j] - mrow[j]);
        __hip_bfloat16 hb = __float2bfloat16(p);
        sP[w][(lk * 4 + j) * 72 + nc * 16 + ln] = *(u16*)&hb;
        lsum[j] += p;
      }

    // drain V(jt) (leave K(jt+1) in flight); BAR_mid: all lanes' V landed
    if (jt + 1 < ntl) { asm volatile("s_waitcnt vmcnt(2)" ::: "memory"); }
    else              { asm volatile("s_waitcnt vmcnt(0)" ::: "memory"); }
    __builtin_amdgcn_sched_barrier(0);
    __builtin_amdgcn_s_barrier();
    __builtin_amdgcn_sched_barrier(0);

    // ---- PV: pipelined tr16 reads of sV ----
    short8 pa0 = *(const short8*)&sP[w][ln * 72 + lk * 8];
    short8 pa1 = *(const short8*)&sP[w][ln * 72 + 32 + lk * 8];

    short4s tb[4][4];
#define TRISSUE(dblk, slot)                                                  \
    {                                                                        \
      const u16* vb = &sV[(lk * 2) * 512 + (dblk) * 64 + ln * 4];            \
      tb[slot][0] = tr16(vb);                                                \
      tb[slot][1] = tr16(vb + 512);                                          \
      tb[slot][2] = tr16(vb + 4096);                                         \
      tb[slot][3] = tr16(vb + 4096 + 512);                                   \
    }
    TRISSUE(0, 0);
    TRISSUE(1, 1);
    asm volatile("s_waitcnt lgkmcnt(8)" ::: "memory");  // pa0/pa1 + batch0 ready? (pa first in order)
    __builtin_amdgcn_sched_barrier(0);

    __builtin_amdgcn_s_setprio(1);
#pragma unroll
    for (int d = 0; d < 8; ++d) {
      if (d < 6) TRISSUE(d + 2, (d + 2) & 3);
      if (d < 6)       asm volatile("s_waitcnt lgkmcnt(8)" ::: "memory");
      else if (d == 6) asm volatile("s_waitcnt lgkmcnt(4)" ::: "memory");
      else             asm volatile("s_waitcnt lgkmcnt(0)" ::: "memory");
      __builtin_amdgcn_sched_barrier(0);
      short8 vb0 = {tb[d & 3][0][0], tb[d & 3][0][1], tb[d & 3][0][2], tb[d & 3][0][3],
                    tb[d & 3][1][0], tb[d & 3][1][1], tb[d & 3][1][2], tb[d & 3][1][3]};
      short8 vb1 = {tb[d & 3][2][0], tb[d & 3][2][1], tb[d & 3][2][2], tb[d & 3][2][3],
                    tb[d & 3][3][0], tb[d & 3][3][1], tb[d & 3][3][2], tb[d & 3][3][3]};
      o[d] = MFMA(pa0, vb0, o[d]);
      o[d] = MFMA(pa1, vb1, o[d]);
    }
    __builtin_amdgcn_s_setprio(0);
#undef TRISSUE

    // BAR_B: all waves done reading V(jt) -> safe to overwrite sV
    __builtin_amdgcn_sched_barrier(0);
    __builtin_amdgcn_s_barrier();
    __builtin_amdgcn_sched_barrier(0);
    if (jt + 1 < ntl) {
      const u16* Vt = Vp + (size_t)(jt + 1) * 64 * 6144;
#pragma unroll
      for (int q = 0; q < 2; ++q) {
        int e = q * 512 + tid;
        int j = ((e >> 6) << 2) + ((e & 7) >> 1);
        int d = (((e >> 3) & 7) << 4) + ((e & 1) << 3);
        gload16(Vt + (size_t)j * 6144 + d, &sV[e * 8]);
      }
      // drain K(jt+1) (leave V(jt+1) in flight); BAR_C: all lanes' K landed
      asm volatile("s_waitcnt vmcnt(2)" ::: "memory");
      __builtin_amdgcn_sched_barrier(0);
      __builtin_amdgcn_s_barrier();
      __builtin_amdgcn_sched_barrier(0);
    }
  }

#pragma unroll
  for (int off = 1; off < 16; off <<= 1)
#pragma unroll
    for (int j = 0; j < 4; ++j) lsum[j] += __shfl_xor(lsum[j], off, 16);
  float inv[4];
#pragma unroll
  for (int j = 0; j < 4; ++j) inv[j] = 1.f / lsum[j];
#pragma unroll
  for (int d = 0; d < 8; ++d)
#pragma unroll
    for (int j = 0; j < 4; ++j)
      out[(size_t)(m0 + w * 16 + lk * 4 + j) * 2048 + h * 128 + d * 16 + ln] =
          f2b(o[d][j] * inv[j]);
}

extern "C" void kernel_launch(void* const* d_in, const int* in_sizes, int n_in,
                              void* d_out, int out_size, void* d_ws, size_t ws_size,
                              hipStream_t stream) {
  const float* x  = (const float*)d_in[0];
  const float* wq = (const float*)d_in[1];
  const float* wk = (const float*)d_in[2];
  const float* wv = (const float*)d_in[3];
  const float* wo = (const float*)d_in[4];
  const float* fc = (const float*)d_in[5];
  const float* fs = (const float*)d_in[6];

  char* ws = (char*)d_ws;
  u16* xb   = (u16*)(ws);
  u16* wqkv = (u16*)(ws + 16777216);
  u16* wob  = (u16*)(ws + 41943040);
  u16* qkv  = (u16*)(ws + 50331648);
  u16* aout = (u16*)(ws + 100663296);

  cast_all<<<24576, 256, 0, stream>>>(x, wq, wk, wv, wo, xb, wqkv, wob);
  gemm_wide<0><<<256, 512, 0, stream>>>(xb, wqkv, qkv, 4096, 6144, 2048);
  rope_k<<<4096, 256, 0, stream>>>(qkv, fc, fs);
  attn_fwd<<<512, 512, 0, stream>>>(qkv, fc, fs, aout);
  gemm_big<2, 1><<<256, 512, 0, stream>>>(aout, wob, d_out, 4096, 2048, 2048);
}

// Round 17
// 226.441 us; speedup vs baseline: 2.4647x; 2.4647x over previous
//
#include <hip/hip_runtime.h>
#include <hip/hip_bf16.h>

typedef unsigned short u16;
typedef __attribute__((ext_vector_type(8))) short short8;
typedef __attribute__((ext_vector_type(4))) short short4s;
typedef __attribute__((ext_vector_type(4))) float f32x4;

__device__ __forceinline__ u16 f2b(float f) {
  union { float f; unsigned u; } c; c.f = f;
  unsigned u = c.u;
  unsigned r = (u + 0x7FFFu + ((u >> 16) & 1u)) >> 16;
  return (u16)r;
}
__device__ __forceinline__ float b2f(u16 h) {
  union { unsigned u; float f; } c; c.u = ((unsigned)h) << 16;
  return c.f;
}

__device__ __forceinline__ void gload16(const u16* g, u16* l) {
  __builtin_amdgcn_global_load_lds((const __attribute__((address_space(1))) void*)g,
                                   (__attribute__((address_space(3))) void*)l, 16, 0, 0);
}

__device__ __forceinline__ short4s tr16(const u16* p) {
  short4s d;
  asm volatile("ds_read_b64_tr_b16 %0, %1"
               : "=v"(d)
               : "v"((const __attribute__((address_space(3))) u16*)p));
  return d;
}

#define MFMA(a, b, c) __builtin_amdgcn_mfma_f32_16x16x32_bf16(a, b, c, 0, 0, 0)

// ---------------- fused cast fp32 -> bf16 (x, wq, wk, wv, wo) -------------
__global__ __launch_bounds__(256) void cast_all(const float* __restrict__ x,
                                                const float* __restrict__ wq,
                                                const float* __restrict__ wk,
                                                const float* __restrict__ wv,
                                                const float* __restrict__ wo,
                                                u16* __restrict__ xb,
                                                u16* __restrict__ wqkv,
                                                u16* __restrict__ wob) {
  int i = blockIdx.x * 256 + threadIdx.x;
  const float4* s; u16* d; int off;
  if (i < 2097152)      { s = (const float4*)x;  d = xb;            off = i; }
  else if (i < 3145728) { s = (const float4*)wq; d = wqkv;          off = i - 2097152; }
  else if (i < 4194304) { s = (const float4*)wk; d = wqkv + 4194304; off = i - 3145728; }
  else if (i < 5242880) { s = (const float4*)wv; d = wqkv + 8388608; off = i - 4194304; }
  else                  { s = (const float4*)wo; d = wob;           off = i - 5242880; }
  float4 v = s[off];
  ushort4 r;
  r.x = f2b(v.x); r.y = f2b(v.y); r.z = f2b(v.z); r.w = f2b(v.w);
  *(ushort4*)(d + (size_t)off * 4) = r;
}

// ---------------- RoPE in-place on K region only (cols 2048..4095) --------
__global__ __launch_bounds__(256) void rope_k(u16* __restrict__ qkv,
                                              const float* __restrict__ fc,
                                              const float* __restrict__ fs) {
  int idx = blockIdx.x * 256 + threadIdx.x;
  int m = idx >> 8;
  int c = idx & 255;
  int s = m & 2047;
  int i0 = (c * 4) & 63;
  u16* p = qkv + (size_t)m * 6144 + 2048 + c * 8;
  short8 v = *(short8*)p;
  float4 cs = *(const float4*)(fc + (size_t)s * 64 + i0);
  float4 sn = *(const float4*)(fs + (size_t)s * 64 + i0);
  float cc[4] = {cs.x, cs.y, cs.z, cs.w};
  float ss[4] = {sn.x, sn.y, sn.z, sn.w};
#pragma unroll
  for (int t = 0; t < 4; ++t) {
    float x0 = b2f((u16)v[2 * t]);
    float x1 = b2f((u16)v[2 * t + 1]);
    float o0 = x0 * cc[t] - x1 * ss[t];
    float o1 = x0 * ss[t] + x1 * cc[t];
    v[2 * t]     = (short)f2b(o0);
    v[2 * t + 1] = (short)f2b(o1);
  }
  *(short8*)p = v;
}

// ---------------- 256x384 bf16 NT GEMM, BK=32 (unchanged R13) -------------
template <int F32OUT>
__global__ __launch_bounds__(512, 2) void gemm_wide(const u16* __restrict__ Ag,
                                                    const u16* __restrict__ Bg,
                                                    void* __restrict__ Cp,
                                                    int M, int N, int K) {
  __shared__ __align__(16) u16 lds[40960];
  const int tid = threadIdx.x;
  const int l = tid & 63, w = tid >> 6;
  const int wm = w >> 2, wn = w & 3;
  const int ln = l & 15, lk = l >> 4;
  const int nbn = N / 384;
  const int nwg = (M >> 8) * nbn;
  const int wg = ((blockIdx.x & 7) * (nwg >> 3)) + (blockIdx.x >> 3);
  const int row0 = (wg / nbn) << 8;
  const int col0 = (wg % nbn) * 384;
  const int T = K >> 5;

#define STAGE_A(t)                                                                     \
  {                                                                                    \
    _Pragma("unroll")                                                                  \
    for (int u = 0; u < 2; ++u) {                                                      \
      int e = u * 512 + tid;                                                           \
      int rr = e >> 2;                                                                 \
      gload16(Ag + (size_t)(row0 + rr) * K + (t) * 32 +                                \
                  (((e & 3) ^ ((rr >> 1) & 3)) << 3),                                  \
              lds + ((t) & 1) * 8192 + e * 8);                                         \
    }                                                                                  \
  }
#define STAGE_B(t)                                                                     \
  {                                                                                    \
    _Pragma("unroll")                                                                  \
    for (int u = 0; u < 3; ++u) {                                                      \
      int e = u * 512 + tid;                                                           \
      int rr = e >> 2;                                                                 \
      gload16(Bg + (size_t)(col0 + rr) * K + (t) * 32 +                                \
                  (((e & 3) ^ ((rr >> 1) & 3)) << 3),                                  \
              lds + 16384 + ((t) & 1) * 12288 + e * 8);                                \
    }                                                                                  \
  }

  f32x4 acc[8][6];
#pragma unroll
  for (int m = 0; m < 8; ++m)
#pragma unroll
    for (int n = 0; n < 6; ++n) acc[m][n] = (f32x4){0.f, 0.f, 0.f, 0.f};

  const int cx = (lk ^ ((ln >> 1) & 3)) << 3;

  STAGE_B(0); STAGE_A(0); STAGE_B(1);
  asm volatile("s_waitcnt vmcnt(3)" ::: "memory");
  __builtin_amdgcn_s_barrier();

  for (int t = 0; t < T; ++t) {
    const u16* aB = lds + (t & 1) * 8192;
    const u16* bB = lds + 16384 + (t & 1) * 12288;
    short8 bf[6];
    short8 af[4];

#pragma unroll
    for (int n = 0; n < 6; ++n)
      bf[n] = *(const short8*)&bB[(wn * 96 + n * 16 + ln) * 32 + cx];
#pragma unroll
    for (int mf = 0; mf < 4; ++mf)
      af[mf] = *(const short8*)&aB[(wm * 128 + mf * 16 + ln) * 32 + cx];
    if (t + 1 < T) STAGE_A(t + 1);
    __builtin_amdgcn_s_setprio(1);
#pragma unroll
    for (int mf = 0; mf < 4; ++mf)
#pragma unroll
      for (int n = 0; n < 6; ++n)
        acc[mf][n] = MFMA(af[mf], bf[n], acc[mf][n]);
    __builtin_amdgcn_s_setprio(0);
    __builtin_amdgcn_s_barrier();

#pragma unroll
    for (int mf = 0; mf < 4; ++mf)
      af[mf] = *(const short8*)&aB[(wm * 128 + (4 + mf) * 16 + ln) * 32 + cx];
    if (t + 2 < T) STAGE_B(t + 2);
    __builtin_amdgcn_s_setprio(1);
#pragma unroll
    for (int mf = 0; mf < 4; ++mf)
#pragma unroll
      for (int n = 0; n < 6; ++n)
        acc[4 + mf][n] = MFMA(af[mf], bf[n], acc[4 + mf][n]);
    __builtin_amdgcn_s_setprio(0);
    if (t + 2 < T) { asm volatile("s_waitcnt vmcnt(3)" ::: "memory"); }
    else           { asm volatile("s_waitcnt vmcnt(0)" ::: "memory"); }
    __builtin_amdgcn_s_barrier();
  }

#pragma unroll
  for (int m = 0; m < 8; ++m) {
    int r0 = row0 + wm * 128 + m * 16 + lk * 4;
#pragma unroll
    for (int n = 0; n < 6; ++n) {
      int cc = col0 + wn * 96 + n * 16 + ln;
#pragma unroll
      for (int j = 0; j < 4; ++j) {
        float v = acc[m][n][j];
        if (F32OUT) ((float*)Cp)[(size_t)(r0 + j) * N + cc] = v;
        else        ((u16*)Cp)[(size_t)(r0 + j) * N + cc]   = f2b(v);
      }
    }
  }
#undef STAGE_A
#undef STAGE_B
}

// ---------------- 256 x 128 NT GEMM (gemm2, unchanged gemm_big<2>) --------
template <int NREP, int F32OUT>
__global__ __launch_bounds__(512, 2) void gemm_big(const u16* __restrict__ Ag,
                                                   const u16* __restrict__ Bg,
                                                   void* __restrict__ Cp,
                                                   int M, int N, int K) {
  __shared__ __align__(16) u16 lds[32768 + NREP * 8192];
  const int tid = threadIdx.x;
  const int l = tid & 63, w = tid >> 6;
  const int wm = w >> 2, wn = w & 3;
  const int ln = l & 15, lk = l >> 4;
  const int BN = NREP * 64;
  const int nbn = N / BN;
  const int nwg = (M >> 8) * nbn;
  const int wg = ((blockIdx.x & 7) * (nwg >> 3)) + (blockIdx.x >> 3);
  const int row0 = (wg / nbn) << 8;
  const int col0 = (wg % nbn) * BN;
  const int T = K >> 6;

#define STAGE_A(t, h)                                                                  \
  {                                                                                    \
    _Pragma("unroll")                                                                  \
    for (int u = 0; u < 2; ++u) {                                                      \
      int e = u * 512 + tid;                                                           \
      int rr = (h) * 128 + (e >> 3);                                                   \
      gload16(Ag + (size_t)(row0 + rr) * K + (t) * 64 + (((e & 7) ^ (rr & 7)) << 3),   \
              lds + ((t) & 1) * 16384 + (h) * 8192 + e * 8);                           \
    }                                                                                  \
  }
#define STAGE_B(t, pb)                                                                 \
  {                                                                                    \
    int rr = (pb) * 64 + (tid >> 3);                                                   \
    gload16(Bg + (size_t)(col0 + rr) * K + (t) * 64 + (((tid & 7) ^ (rr & 7)) << 3),   \
            lds + 32768 + ((t) & 1) * NREP * 4096 + (pb) * 4096 + tid * 8);            \
  }

  f32x4 acc[8][NREP];
#pragma unroll
  for (int m = 0; m < 8; ++m)
#pragma unroll
    for (int n = 0; n < NREP; ++n) acc[m][n] = (f32x4){0.f, 0.f, 0.f, 0.f};

  const int x = ln & 7;
  const int c0 = (lk ^ x) << 3;
  const int c1 = ((4 + lk) ^ x) << 3;

#pragma unroll
  for (int pb = 0; pb < NREP; ++pb) STAGE_B(0, pb);
  STAGE_A(0, 0); STAGE_A(0, 1);
#pragma unroll
  for (int pb = 0; pb < NREP; ++pb) STAGE_B(1, pb);
  asm volatile("s_waitcnt vmcnt(2)" ::: "memory");
  __builtin_amdgcn_s_barrier();

  for (int t = 0; t < T; ++t) {
    const u16* aB = lds + (t & 1) * 16384 + wm * 8192;
    const u16* bB = lds + 32768 + (t & 1) * NREP * 4096;
    short8 bf[NREP][2];
#pragma unroll
    for (int p = 0; p < 4; ++p) {
      if (p == 0) {
#pragma unroll
        for (int n = 0; n < NREP; ++n) {
          int rb = (wn * NREP * 16 + n * 16 + ln) * 64;
          bf[n][0] = *(const short8*)&bB[rb + c0];
          bf[n][1] = *(const short8*)&bB[rb + c1];
        }
      }
      short8 af[2][2];
#pragma unroll
      for (int m2 = 0; m2 < 2; ++m2) {
        int ra = ((p * 2 + m2) * 16 + ln) * 64;
        af[m2][0] = *(const short8*)&aB[ra + c0];
        af[m2][1] = *(const short8*)&aB[ra + c1];
      }
      if (p == 0)      { if (t + 1 < T) STAGE_A(t + 1, 0); }
      else if (p == 1) { if (t + 1 < T) STAGE_A(t + 1, 1);
                         if (t + 2 < T) STAGE_B(t + 2, 0); }
      else if (p == 2) { if (t + 2 < T) STAGE_B(t + 2, 1); }

      __builtin_amdgcn_s_setprio(1);
#pragma unroll
      for (int m2 = 0; m2 < 2; ++m2)
#pragma unroll
        for (int n = 0; n < NREP; ++n)
#pragma unroll
          for (int kk = 0; kk < 2; ++kk)
            acc[p * 2 + m2][n] = MFMA(af[m2][kk], bf[n][kk], acc[p * 2 + m2][n]);
      __builtin_amdgcn_s_setprio(0);

      if (p == 3) {
        if (t + 2 < T)      { asm volatile("s_waitcnt vmcnt(2)" ::: "memory"); }
        else if (t + 1 < T) { asm volatile("s_waitcnt vmcnt(0)" ::: "memory"); }
      }
      __builtin_amdgcn_s_barrier();
    }
  }

#pragma unroll
  for (int m = 0; m < 8; ++m) {
    int r0 = row0 + wm * 128 + m * 16 + lk * 4;
#pragma unroll
    for (int n = 0; n < NREP; ++n) {
      int cc = col0 + wn * NREP * 16 + n * 16 + ln;
#pragma unroll
      for (int j = 0; j < 4; ++j) {
        float v = acc[m][n][j];
        if (F32OUT) ((float*)Cp)[(size_t)(r0 + j) * N + cc] = v;
        else        ((u16*)Cp)[(size_t)(r0 + j) * N + cc]   = f2b(v);
      }
    }
  }
#undef STAGE_A
#undef STAGE_B
}

// ---------------- flash attention: causal, hd=128, H=16 (R15-exact) -------
// Balanced 512-block split: bids 0..255 carry qt in {8..15} (big, first),
// bids 256..511 the complementary qt in {0..7}; CU i gets bids i and i+256
// -> per-CU work = 34 tiles constant, 2 blocks/CU (LDS 67.6 KB) co-resident.
// Single-buffer K (raw s_barrier after QK, stage K(t+1) in place), V double-
// buffered. P-diet: compiler bf16 cast, lsum from unrounded p. tr16 batches
// 0/1 hoisted above exp/P-store.
__global__ __launch_bounds__(512, 4) void attn_fwd(const u16* __restrict__ qkv,
                                                   const float* __restrict__ fc,
                                                   const float* __restrict__ fs,
                                                   u16* __restrict__ out) {
  __shared__ __align__(16) u16 sK[64 * 128];
  __shared__ __align__(16) u16 sV[2][64 * 128];
  __shared__ __align__(16) u16 sP[8][16 * 72];
  const int tid = threadIdx.x, l = tid & 63, w = tid >> 6;   // w 0..7
  const int ln = l & 15, lk = l >> 4;

  const int bid = blockIdx.x;                 // 512 blocks
  const int idx = bid & 255, half = bid >> 8;
  const int l0 = ((idx & 7) << 5) | (idx >> 3);   // XCD-cluster (0..255)
  const int bh = l0 >> 3, pr = l0 & 7;
  const int qt = half ? pr : (15 - pr);       // big tiles in first 256 bids
  const int b = bh >> 4, h = bh & 15;

  const u16* Kp = qkv + (size_t)b * 2048 * 6144 + 2048 + h * 128;
  const u16* Vp = Kp + 2048;
  const float scale = 0.08838834764831845f;

  const int m0 = b * 2048 + qt * 128;
  const u16* Qp = qkv + (size_t)m0 * 6144 + h * 128;
  const int srow = qt * 128 + w * 16 + ln;

  short8 qf[4];
#pragma unroll
  for (int kc = 0; kc < 4; ++kc) {
    short8 raw = *(const short8*)(Qp + (size_t)(w * 16 + ln) * 6144 + kc * 32 + lk * 8);
    float4 c4 = *(const float4*)(fc + (size_t)srow * 64 + kc * 16 + lk * 4);
    float4 s4 = *(const float4*)(fs + (size_t)srow * 64 + kc * 16 + lk * 4);
    float cc[4] = {c4.x * scale, c4.y * scale, c4.z * scale, c4.w * scale};
    float ss[4] = {s4.x * scale, s4.y * scale, s4.z * scale, s4.w * scale};
#pragma unroll
    for (int t = 0; t < 4; ++t) {
      float x0 = b2f((u16)raw[2 * t]);
      float x1 = b2f((u16)raw[2 * t + 1]);
      qf[kc][2 * t]     = (short)f2b(x0 * cc[t] - x1 * ss[t]);
      qf[kc][2 * t + 1] = (short)f2b(x0 * ss[t] + x1 * cc[t]);
    }
  }

  f32x4 o[8];
#pragma unroll
  for (int d = 0; d < 8; ++d) o[d] = (f32x4){0.f, 0.f, 0.f, 0.f};
  float mrow[4] = {-1e9f, -1e9f, -1e9f, -1e9f};
  float lsum[4] = {0.f, 0.f, 0.f, 0.f};

  const int ntl = 2 * qt + 2;

  // prologue: K(0) -> sK, V(0) -> sV[0]
  {
#pragma unroll
    for (int q = 0; q < 2; ++q) {
      int e = q * 512 + tid;
      int r = e >> 4, p = e & 15;
      gload16(Kp + (size_t)r * 6144 + ((p ^ (r & 7)) << 3), &sK[e * 8]);
      int j = ((e >> 6) << 2) + ((e & 7) >> 1);
      int d = (((e >> 3) & 7) << 4) + ((e & 1) << 3);
      gload16(Vp + (size_t)j * 6144 + d, &sV[0][e * 8]);
    }
  }
  __syncthreads();

  int cur = 0;
  for (int jt = 0; jt < ntl; ++jt) {
    // stage V(t+1) early (full-tile cover, double-buffered)
    if (jt + 1 < ntl) {
      const u16* Vt = Vp + (size_t)(jt + 1) * 64 * 6144;
      int nb = cur ^ 1;
#pragma unroll
      for (int q = 0; q < 2; ++q) {
        int e = q * 512 + tid;
        int j = ((e >> 6) << 2) + ((e & 7) >> 1);
        int d = (((e >> 3) & 7) << 4) + ((e & 1) << 3);
        gload16(Vt + (size_t)j * 6144 + d, &sV[nb][e * 8]);
      }
    }

    // ---- QK^T from single-buffered sK ----
    f32x4 sf[4];
    __builtin_amdgcn_s_setprio(1);
#pragma unroll
    for (int nc = 0; nc < 4; ++nc) {
      f32x4 s = (f32x4){0.f, 0.f, 0.f, 0.f};
#pragma unroll
      for (int kc = 0; kc < 4; ++kc) {
        int r = nc * 16 + ln;
        short8 kb = *(const short8*)&sK[r * 128 + (((kc << 2) + lk) ^ (r & 7)) * 8];
        s = MFMA(qf[kc], kb, s);
      }
      sf[nc] = s;
    }
    __builtin_amdgcn_s_setprio(0);

    // all waves done reading K -> safe to overwrite sK with K(t+1)
    __builtin_amdgcn_sched_barrier(0);
    __builtin_amdgcn_s_barrier();
    __builtin_amdgcn_sched_barrier(0);
    if (jt + 1 < ntl) {
      const u16* Kt = Kp + (size_t)(jt + 1) * 64 * 6144;
#pragma unroll
      for (int q = 0; q < 2; ++q) {
        int e = q * 512 + tid;
        int r = e >> 4, p = e & 15;
        gload16(Kt + (size_t)r * 6144 + ((p ^ (r & 7)) << 3), &sK[e * 8]);
      }
    }

    // causal mask on diagonal-crossing tiles
    if (jt >= 2 * qt) {
      int ig = qt * 128 + w * 16 + lk * 4;
#pragma unroll
      for (int nc = 0; nc < 4; ++nc) {
        int jg = jt * 64 + nc * 16 + ln;
#pragma unroll
        for (int j = 0; j < 4; ++j)
          sf[nc][j] = (jg > ig + j) ? -1e9f : sf[nc][j];
      }
    }

    // ---- defer-max ----
    float tm[4];
#pragma unroll
    for (int j = 0; j < 4; ++j)
      tm[j] = fmaxf(fmaxf(sf[0][j], sf[1][j]), fmaxf(sf[2][j], sf[3][j]));
    int ok = (tm[0] <= mrow[0] + 8.f) & (tm[1] <= mrow[1] + 8.f) &
             (tm[2] <= mrow[2] + 8.f) & (tm[3] <= mrow[3] + 8.f);
    if (!__all(ok)) {
#pragma unroll
      for (int off = 1; off < 16; off <<= 1)
#pragma unroll
        for (int j = 0; j < 4; ++j) tm[j] = fmaxf(tm[j], __shfl_xor(tm[j], off, 16));
      float al[4];
#pragma unroll
      for (int j = 0; j < 4; ++j) {
        float nm = fmaxf(mrow[j], tm[j]);
        al[j] = __expf(mrow[j] - nm);
        mrow[j] = nm;
      }
#pragma unroll
      for (int d = 0; d < 8; ++d)
#pragma unroll
        for (int j = 0; j < 4; ++j) o[d][j] *= al[j];
#pragma unroll
      for (int j = 0; j < 4; ++j) lsum[j] *= al[j];
    }

    // ---- hoisted V tr16 batches 0,1 (latency hides under exp below) ----
    short4s tb[4][4];
#define TRISSUE(dblk, slot)                                                  \
    {                                                                        \
      const u16* vb = &sV[cur][(lk * 2) * 512 + (dblk) * 64 + ln * 4];       \
      tb[slot][0] = tr16(vb);                                                \
      tb[slot][1] = tr16(vb + 512);                                          \
      tb[slot][2] = tr16(vb + 4096);                                         \
      tb[slot][3] = tr16(vb + 4096 + 512);                                   \
    }
    TRISSUE(0, 0);
    TRISSUE(1, 1);

    // ---- P = exp(S - m): compiler bf16 cast; lsum from unrounded p ----
#pragma unroll
    for (int nc = 0; nc < 4; ++nc)
#pragma unroll
      for (int j = 0; j < 4; ++j) {
        float p = __expf(sf[nc][j] - mrow[j]);
        __hip_bfloat16 hb = __float2bfloat16(p);
        sP[w][(lk * 4 + j) * 72 + nc * 16 + ln] = *(u16*)&hb;
        lsum[j] += p;
      }

    short8 pa0 = *(const short8*)&sP[w][ln * 72 + lk * 8];
    short8 pa1 = *(const short8*)&sP[w][ln * 72 + 32 + lk * 8];
    asm volatile("s_waitcnt lgkmcnt(0)" ::: "memory");
    __builtin_amdgcn_sched_barrier(0);

    __builtin_amdgcn_s_setprio(1);
#pragma unroll
    for (int d = 0; d < 8; ++d) {
      if (d < 6) TRISSUE(d + 2, (d + 2) & 3);
      if (d < 6)       asm volatile("s_waitcnt lgkmcnt(8)" ::: "memory");
      else if (d == 6) asm volatile("s_waitcnt lgkmcnt(4)" ::: "memory");
      else             asm volatile("s_waitcnt lgkmcnt(0)" ::: "memory");
      __builtin_amdgcn_sched_barrier(0);
      short8 vb0 = {tb[d & 3][0][0], tb[d & 3][0][1], tb[d & 3][0][2], tb[d & 3][0][3],
                    tb[d & 3][1][0], tb[d & 3][1][1], tb[d & 3][1][2], tb[d & 3][1][3]};
      short8 vb1 = {tb[d & 3][2][0], tb[d & 3][2][1], tb[d & 3][2][2], tb[d & 3][2][3],
                    tb[d & 3][3][0], tb[d & 3][3][1], tb[d & 3][3][2], tb[d & 3][3][3]};
      o[d] = MFMA(pa0, vb0, o[d]);
      o[d] = MFMA(pa1, vb1, o[d]);
    }
    __builtin_amdgcn_s_setprio(0);
#undef TRISSUE

    __syncthreads();
    cur ^= 1;
  }

#pragma unroll
  for (int off = 1; off < 16; off <<= 1)
#pragma unroll
    for (int j = 0; j < 4; ++j) lsum[j] += __shfl_xor(lsum[j], off, 16);
  float inv[4];
#pragma unroll
  for (int j = 0; j < 4; ++j) inv[j] = 1.f / lsum[j];
#pragma unroll
  for (int d = 0; d < 8; ++d)
#pragma unroll
    for (int j = 0; j < 4; ++j)
      out[(size_t)(m0 + w * 16 + lk * 4 + j) * 2048 + h * 128 + d * 16 + ln] =
          f2b(o[d][j] * inv[j]);
}

extern "C" void kernel_launch(void* const* d_in, const int* in_sizes, int n_in,
                              void* d_out, int out_size, void* d_ws, size_t ws_size,
                              hipStream_t stream) {
  const float* x  = (const float*)d_in[0];
  const float* wq = (const float*)d_in[1];
  const float* wk = (const float*)d_in[2];
  const float* wv = (const float*)d_in[3];
  const float* wo = (const float*)d_in[4];
  const float* fc = (const float*)d_in[5];
  const float* fs = (const float*)d_in[6];

  char* ws = (char*)d_ws;
  u16* xb   = (u16*)(ws);
  u16* wqkv = (u16*)(ws + 16777216);
  u16* wob  = (u16*)(ws + 41943040);
  u16* qkv  = (u16*)(ws + 50331648);
  u16* aout = (u16*)(ws + 100663296);

  cast_all<<<24576, 256, 0, stream>>>(x, wq, wk, wv, wo, xb, wqkv, wob);
  gemm_wide<0><<<256, 512, 0, stream>>>(xb, wqkv, qkv, 4096, 6144, 2048);
  rope_k<<<4096, 256, 0, stream>>>(qkv, fc, fs);
  attn_fwd<<<512, 512, 0, stream>>>(qkv, fc, fs, aout);
  gemm_big<2, 1><<<256, 512, 0, stream>>>(aout, wob, d_out, 4096, 2048, 2048);
}

// Round 18
// 226.092 us; speedup vs baseline: 2.4685x; 1.0015x over previous
//
#include <hip/hip_runtime.h>
#include <hip/hip_bf16.h>

typedef unsigned short u16;
typedef __attribute__((ext_vector_type(8))) short short8;
typedef __attribute__((ext_vector_type(4))) short short4s;
typedef __attribute__((ext_vector_type(4))) float f32x4;

__device__ __forceinline__ u16 f2b(float f) {
  union { float f; unsigned u; } c; c.f = f;
  unsigned u = c.u;
  unsigned r = (u + 0x7FFFu + ((u >> 16) & 1u)) >> 16;
  return (u16)r;
}
__device__ __forceinline__ float b2f(u16 h) {
  union { unsigned u; float f; } c; c.u = ((unsigned)h) << 16;
  return c.f;
}

__device__ __forceinline__ void gload16(const u16* g, u16* l) {
  __builtin_amdgcn_global_load_lds((const __attribute__((address_space(1))) void*)g,
                                   (__attribute__((address_space(3))) void*)l, 16, 0, 0);
}

__device__ __forceinline__ short4s tr16(const u16* p) {
  short4s d;
  asm volatile("ds_read_b64_tr_b16 %0, %1"
               : "=v"(d)
               : "v"((const __attribute__((address_space(3))) u16*)p));
  return d;
}

#define MFMA(a, b, c) __builtin_amdgcn_mfma_f32_16x16x32_bf16(a, b, c, 0, 0, 0)

// ---------------- fused cast fp32 -> bf16 (x, wq, wk, wv, wo) -------------
__global__ __launch_bounds__(256) void cast_all(const float* __restrict__ x,
                                                const float* __restrict__ wq,
                                                const float* __restrict__ wk,
                                                const float* __restrict__ wv,
                                                const float* __restrict__ wo,
                                                u16* __restrict__ xb,
                                                u16* __restrict__ wqkv,
                                                u16* __restrict__ wob) {
  int i = blockIdx.x * 256 + threadIdx.x;
  const float4* s; u16* d; int off;
  if (i < 2097152)      { s = (const float4*)x;  d = xb;            off = i; }
  else if (i < 3145728) { s = (const float4*)wq; d = wqkv;          off = i - 2097152; }
  else if (i < 4194304) { s = (const float4*)wk; d = wqkv + 4194304; off = i - 3145728; }
  else if (i < 5242880) { s = (const float4*)wv; d = wqkv + 8388608; off = i - 4194304; }
  else                  { s = (const float4*)wo; d = wob;           off = i - 5242880; }
  float4 v = s[off];
  ushort4 r;
  r.x = f2b(v.x); r.y = f2b(v.y); r.z = f2b(v.z); r.w = f2b(v.w);
  *(ushort4*)(d + (size_t)off * 4) = r;
}

// ---------------- RoPE in-place on K region only (cols 2048..4095) --------
__global__ __launch_bounds__(256) void rope_k(u16* __restrict__ qkv,
                                              const float* __restrict__ fc,
                                              const float* __restrict__ fs) {
  int idx = blockIdx.x * 256 + threadIdx.x;
  int m = idx >> 8;
  int c = idx & 255;
  int s = m & 2047;
  int i0 = (c * 4) & 63;
  u16* p = qkv + (size_t)m * 6144 + 2048 + c * 8;
  short8 v = *(short8*)p;
  float4 cs = *(const float4*)(fc + (size_t)s * 64 + i0);
  float4 sn = *(const float4*)(fs + (size_t)s * 64 + i0);
  float cc[4] = {cs.x, cs.y, cs.z, cs.w};
  float ss[4] = {sn.x, sn.y, sn.z, sn.w};
#pragma unroll
  for (int t = 0; t < 4; ++t) {
    float x0 = b2f((u16)v[2 * t]);
    float x1 = b2f((u16)v[2 * t + 1]);
    float o0 = x0 * cc[t] - x1 * ss[t];
    float o1 = x0 * ss[t] + x1 * cc[t];
    v[2 * t]     = (short)f2b(o0);
    v[2 * t + 1] = (short)f2b(o1);
  }
  *(short8*)p = v;
}

// ---------------- 256x384 bf16 NT GEMM, BK=32 (unchanged R13) -------------
template <int F32OUT>
__global__ __launch_bounds__(512, 2) void gemm_wide(const u16* __restrict__ Ag,
                                                    const u16* __restrict__ Bg,
                                                    void* __restrict__ Cp,
                                                    int M, int N, int K) {
  __shared__ __align__(16) u16 lds[40960];
  const int tid = threadIdx.x;
  const int l = tid & 63, w = tid >> 6;
  const int wm = w >> 2, wn = w & 3;
  const int ln = l & 15, lk = l >> 4;
  const int nbn = N / 384;
  const int nwg = (M >> 8) * nbn;
  const int wg = ((blockIdx.x & 7) * (nwg >> 3)) + (blockIdx.x >> 3);
  const int row0 = (wg / nbn) << 8;
  const int col0 = (wg % nbn) * 384;
  const int T = K >> 5;

#define STAGE_A(t)                                                                     \
  {                                                                                    \
    _Pragma("unroll")                                                                  \
    for (int u = 0; u < 2; ++u) {                                                      \
      int e = u * 512 + tid;                                                           \
      int rr = e >> 2;                                                                 \
      gload16(Ag + (size_t)(row0 + rr) * K + (t) * 32 +                                \
                  (((e & 3) ^ ((rr >> 1) & 3)) << 3),                                  \
              lds + ((t) & 1) * 8192 + e * 8);                                         \
    }                                                                                  \
  }
#define STAGE_B(t)                                                                     \
  {                                                                                    \
    _Pragma("unroll")                                                                  \
    for (int u = 0; u < 3; ++u) {                                                      \
      int e = u * 512 + tid;                                                           \
      int rr = e >> 2;                                                                 \
      gload16(Bg + (size_t)(col0 + rr) * K + (t) * 32 +                                \
                  (((e & 3) ^ ((rr >> 1) & 3)) << 3),                                  \
              lds + 16384 + ((t) & 1) * 12288 + e * 8);                                \
    }                                                                                  \
  }

  f32x4 acc[8][6];
#pragma unroll
  for (int m = 0; m < 8; ++m)
#pragma unroll
    for (int n = 0; n < 6; ++n) acc[m][n] = (f32x4){0.f, 0.f, 0.f, 0.f};

  const int cx = (lk ^ ((ln >> 1) & 3)) << 3;

  STAGE_B(0); STAGE_A(0); STAGE_B(1);
  asm volatile("s_waitcnt vmcnt(3)" ::: "memory");
  __builtin_amdgcn_s_barrier();

  for (int t = 0; t < T; ++t) {
    const u16* aB = lds + (t & 1) * 8192;
    const u16* bB = lds + 16384 + (t & 1) * 12288;
    short8 bf[6];
    short8 af[4];

#pragma unroll
    for (int n = 0; n < 6; ++n)
      bf[n] = *(const short8*)&bB[(wn * 96 + n * 16 + ln) * 32 + cx];
#pragma unroll
    for (int mf = 0; mf < 4; ++mf)
      af[mf] = *(const short8*)&aB[(wm * 128 + mf * 16 + ln) * 32 + cx];
    if (t + 1 < T) STAGE_A(t + 1);
    __builtin_amdgcn_s_setprio(1);
#pragma unroll
    for (int mf = 0; mf < 4; ++mf)
#pragma unroll
      for (int n = 0; n < 6; ++n)
        acc[mf][n] = MFMA(af[mf], bf[n], acc[mf][n]);
    __builtin_amdgcn_s_setprio(0);
    __builtin_amdgcn_s_barrier();

#pragma unroll
    for (int mf = 0; mf < 4; ++mf)
      af[mf] = *(const short8*)&aB[(wm * 128 + (4 + mf) * 16 + ln) * 32 + cx];
    if (t + 2 < T) STAGE_B(t + 2);
    __builtin_amdgcn_s_setprio(1);
#pragma unroll
    for (int mf = 0; mf < 4; ++mf)
#pragma unroll
      for (int n = 0; n < 6; ++n)
        acc[4 + mf][n] = MFMA(af[mf], bf[n], acc[4 + mf][n]);
    __builtin_amdgcn_s_setprio(0);
    if (t + 2 < T) { asm volatile("s_waitcnt vmcnt(3)" ::: "memory"); }
    else           { asm volatile("s_waitcnt vmcnt(0)" ::: "memory"); }
    __builtin_amdgcn_s_barrier();
  }

#pragma unroll
  for (int m = 0; m < 8; ++m) {
    int r0 = row0 + wm * 128 + m * 16 + lk * 4;
#pragma unroll
    for (int n = 0; n < 6; ++n) {
      int cc = col0 + wn * 96 + n * 16 + ln;
#pragma unroll
      for (int j = 0; j < 4; ++j) {
        float v = acc[m][n][j];
        if (F32OUT) ((float*)Cp)[(size_t)(r0 + j) * N + cc] = v;
        else        ((u16*)Cp)[(size_t)(r0 + j) * N + cc]   = f2b(v);
      }
    }
  }
#undef STAGE_A
#undef STAGE_B
}

// ---------------- 256 x 128 NT GEMM (gemm2, unchanged gemm_big<2>) --------
template <int NREP, int F32OUT>
__global__ __launch_bounds__(512, 2) void gemm_big(const u16* __restrict__ Ag,
                                                   const u16* __restrict__ Bg,
                                                   void* __restrict__ Cp,
                                                   int M, int N, int K) {
  __shared__ __align__(16) u16 lds[32768 + NREP * 8192];
  const int tid = threadIdx.x;
  const int l = tid & 63, w = tid >> 6;
  const int wm = w >> 2, wn = w & 3;
  const int ln = l & 15, lk = l >> 4;
  const int BN = NREP * 64;
  const int nbn = N / BN;
  const int nwg = (M >> 8) * nbn;
  const int wg = ((blockIdx.x & 7) * (nwg >> 3)) + (blockIdx.x >> 3);
  const int row0 = (wg / nbn) << 8;
  const int col0 = (wg % nbn) * BN;
  const int T = K >> 6;

#define STAGE_A(t, h)                                                                  \
  {                                                                                    \
    _Pragma("unroll")                                                                  \
    for (int u = 0; u < 2; ++u) {                                                      \
      int e = u * 512 + tid;                                                           \
      int rr = (h) * 128 + (e >> 3);                                                   \
      gload16(Ag + (size_t)(row0 + rr) * K + (t) * 64 + (((e & 7) ^ (rr & 7)) << 3),   \
              lds + ((t) & 1) * 16384 + (h) * 8192 + e * 8);                           \
    }                                                                                  \
  }
#define STAGE_B(t, pb)                                                                 \
  {                                                                                    \
    int rr = (pb) * 64 + (tid >> 3);                                                   \
    gload16(Bg + (size_t)(col0 + rr) * K + (t) * 64 + (((tid & 7) ^ (rr & 7)) << 3),   \
            lds + 32768 + ((t) & 1) * NREP * 4096 + (pb) * 4096 + tid * 8);            \
  }

  f32x4 acc[8][NREP];
#pragma unroll
  for (int m = 0; m < 8; ++m)
#pragma unroll
    for (int n = 0; n < NREP; ++n) acc[m][n] = (f32x4){0.f, 0.f, 0.f, 0.f};

  const int x = ln & 7;
  const int c0 = (lk ^ x) << 3;
  const int c1 = ((4 + lk) ^ x) << 3;

#pragma unroll
  for (int pb = 0; pb < NREP; ++pb) STAGE_B(0, pb);
  STAGE_A(0, 0); STAGE_A(0, 1);
#pragma unroll
  for (int pb = 0; pb < NREP; ++pb) STAGE_B(1, pb);
  asm volatile("s_waitcnt vmcnt(2)" ::: "memory");
  __builtin_amdgcn_s_barrier();

  for (int t = 0; t < T; ++t) {
    const u16* aB = lds + (t & 1) * 16384 + wm * 8192;
    const u16* bB = lds + 32768 + (t & 1) * NREP * 4096;
    short8 bf[NREP][2];
#pragma unroll
    for (int p = 0; p < 4; ++p) {
      if (p == 0) {
#pragma unroll
        for (int n = 0; n < NREP; ++n) {
          int rb = (wn * NREP * 16 + n * 16 + ln) * 64;
          bf[n][0] = *(const short8*)&bB[rb + c0];
          bf[n][1] = *(const short8*)&bB[rb + c1];
        }
      }
      short8 af[2][2];
#pragma unroll
      for (int m2 = 0; m2 < 2; ++m2) {
        int ra = ((p * 2 + m2) * 16 + ln) * 64;
        af[m2][0] = *(const short8*)&aB[ra + c0];
        af[m2][1] = *(const short8*)&aB[ra + c1];
      }
      if (p == 0)      { if (t + 1 < T) STAGE_A(t + 1, 0); }
      else if (p == 1) { if (t + 1 < T) STAGE_A(t + 1, 1);
                         if (t + 2 < T) STAGE_B(t + 2, 0); }
      else if (p == 2) { if (t + 2 < T) STAGE_B(t + 2, 1); }

      __builtin_amdgcn_s_setprio(1);
#pragma unroll
      for (int m2 = 0; m2 < 2; ++m2)
#pragma unroll
        for (int n = 0; n < NREP; ++n)
#pragma unroll
          for (int kk = 0; kk < 2; ++kk)
            acc[p * 2 + m2][n] = MFMA(af[m2][kk], bf[n][kk], acc[p * 2 + m2][n]);
      __builtin_amdgcn_s_setprio(0);

      if (p == 3) {
        if (t + 2 < T)      { asm volatile("s_waitcnt vmcnt(2)" ::: "memory"); }
        else if (t + 1 < T) { asm volatile("s_waitcnt vmcnt(0)" ::: "memory"); }
      }
      __builtin_amdgcn_s_barrier();
    }
  }

#pragma unroll
  for (int m = 0; m < 8; ++m) {
    int r0 = row0 + wm * 128 + m * 16 + lk * 4;
#pragma unroll
    for (int n = 0; n < NREP; ++n) {
      int cc = col0 + wn * NREP * 16 + n * 16 + ln;
#pragma unroll
      for (int j = 0; j < 4; ++j) {
        float v = acc[m][n][j];
        if (F32OUT) ((float*)Cp)[(size_t)(r0 + j) * N + cc] = v;
        else        ((u16*)Cp)[(size_t)(r0 + j) * N + cc]   = f2b(v);
      }
    }
  }
#undef STAGE_A
#undef STAGE_B
}

// ---------------- flash attention: causal, hd=128, H=16 -------------------
// R15 structure; only change vs R17: PV tr16 pipeline depth 2 -> 3
// (issue batch d+3, counted lgkmcnt(12); rotating tb[4], WAR distance 3).
__global__ __launch_bounds__(512, 4) void attn_fwd(const u16* __restrict__ qkv,
                                                   const float* __restrict__ fc,
                                                   const float* __restrict__ fs,
                                                   u16* __restrict__ out) {
  __shared__ __align__(16) u16 sK[64 * 128];
  __shared__ __align__(16) u16 sV[2][64 * 128];
  __shared__ __align__(16) u16 sP[8][16 * 72];
  const int tid = threadIdx.x, l = tid & 63, w = tid >> 6;   // w 0..7
  const int ln = l & 15, lk = l >> 4;

  const int bid = blockIdx.x;                 // 512 blocks
  const int idx = bid & 255, half = bid >> 8;
  const int l0 = ((idx & 7) << 5) | (idx >> 3);   // XCD-cluster (0..255)
  const int bh = l0 >> 3, pr = l0 & 7;
  const int qt = half ? pr : (15 - pr);       // big tiles in first 256 bids
  const int b = bh >> 4, h = bh & 15;

  const u16* Kp = qkv + (size_t)b * 2048 * 6144 + 2048 + h * 128;
  const u16* Vp = Kp + 2048;
  const float scale = 0.08838834764831845f;

  const int m0 = b * 2048 + qt * 128;
  const u16* Qp = qkv + (size_t)m0 * 6144 + h * 128;
  const int srow = qt * 128 + w * 16 + ln;

  short8 qf[4];
#pragma unroll
  for (int kc = 0; kc < 4; ++kc) {
    short8 raw = *(const short8*)(Qp + (size_t)(w * 16 + ln) * 6144 + kc * 32 + lk * 8);
    float4 c4 = *(const float4*)(fc + (size_t)srow * 64 + kc * 16 + lk * 4);
    float4 s4 = *(const float4*)(fs + (size_t)srow * 64 + kc * 16 + lk * 4);
    float cc[4] = {c4.x * scale, c4.y * scale, c4.z * scale, c4.w * scale};
    float ss[4] = {s4.x * scale, s4.y * scale, s4.z * scale, s4.w * scale};
#pragma unroll
    for (int t = 0; t < 4; ++t) {
      float x0 = b2f((u16)raw[2 * t]);
      float x1 = b2f((u16)raw[2 * t + 1]);
      qf[kc][2 * t]     = (short)f2b(x0 * cc[t] - x1 * ss[t]);
      qf[kc][2 * t + 1] = (short)f2b(x0 * ss[t] + x1 * cc[t]);
    }
  }

  f32x4 o[8];
#pragma unroll
  for (int d = 0; d < 8; ++d) o[d] = (f32x4){0.f, 0.f, 0.f, 0.f};
  float mrow[4] = {-1e9f, -1e9f, -1e9f, -1e9f};
  float lsum[4] = {0.f, 0.f, 0.f, 0.f};

  const int ntl = 2 * qt + 2;

  // prologue: K(0) -> sK, V(0) -> sV[0]
  {
#pragma unroll
    for (int q = 0; q < 2; ++q) {
      int e = q * 512 + tid;
      int r = e >> 4, p = e & 15;
      gload16(Kp + (size_t)r * 6144 + ((p ^ (r & 7)) << 3), &sK[e * 8]);
      int j = ((e >> 6) << 2) + ((e & 7) >> 1);
      int d = (((e >> 3) & 7) << 4) + ((e & 1) << 3);
      gload16(Vp + (size_t)j * 6144 + d, &sV[0][e * 8]);
    }
  }
  __syncthreads();

  int cur = 0;
  for (int jt = 0; jt < ntl; ++jt) {
    // stage V(t+1) early (full-tile cover, double-buffered)
    if (jt + 1 < ntl) {
      const u16* Vt = Vp + (size_t)(jt + 1) * 64 * 6144;
      int nb = cur ^ 1;
#pragma unroll
      for (int q = 0; q < 2; ++q) {
        int e = q * 512 + tid;
        int j = ((e >> 6) << 2) + ((e & 7) >> 1);
        int d = (((e >> 3) & 7) << 4) + ((e & 1) << 3);
        gload16(Vt + (size_t)j * 6144 + d, &sV[nb][e * 8]);
      }
    }

    // ---- QK^T from single-buffered sK ----
    f32x4 sf[4];
    __builtin_amdgcn_s_setprio(1);
#pragma unroll
    for (int nc = 0; nc < 4; ++nc) {
      f32x4 s = (f32x4){0.f, 0.f, 0.f, 0.f};
#pragma unroll
      for (int kc = 0; kc < 4; ++kc) {
        int r = nc * 16 + ln;
        short8 kb = *(const short8*)&sK[r * 128 + (((kc << 2) + lk) ^ (r & 7)) * 8];
        s = MFMA(qf[kc], kb, s);
      }
      sf[nc] = s;
    }
    __builtin_amdgcn_s_setprio(0);

    // all waves done reading K -> safe to overwrite sK with K(t+1)
    __builtin_amdgcn_sched_barrier(0);
    __builtin_amdgcn_s_barrier();
    __builtin_amdgcn_sched_barrier(0);
    if (jt + 1 < ntl) {
      const u16* Kt = Kp + (size_t)(jt + 1) * 64 * 6144;
#pragma unroll
      for (int q = 0; q < 2; ++q) {
        int e = q * 512 + tid;
        int r = e >> 4, p = e & 15;
        gload16(Kt + (size_t)r * 6144 + ((p ^ (r & 7)) << 3), &sK[e * 8]);
      }
    }

    // causal mask on diagonal-crossing tiles
    if (jt >= 2 * qt) {
      int ig = qt * 128 + w * 16 + lk * 4;
#pragma unroll
      for (int nc = 0; nc < 4; ++nc) {
        int jg = jt * 64 + nc * 16 + ln;
#pragma unroll
        for (int j = 0; j < 4; ++j)
          sf[nc][j] = (jg > ig + j) ? -1e9f : sf[nc][j];
      }
    }

    // ---- defer-max ----
    float tm[4];
#pragma unroll
    for (int j = 0; j < 4; ++j)
      tm[j] = fmaxf(fmaxf(sf[0][j], sf[1][j]), fmaxf(sf[2][j], sf[3][j]));
    int ok = (tm[0] <= mrow[0] + 8.f) & (tm[1] <= mrow[1] + 8.f) &
             (tm[2] <= mrow[2] + 8.f) & (tm[3] <= mrow[3] + 8.f);
    if (!__all(ok)) {
#pragma unroll
      for (int off = 1; off < 16; off <<= 1)
#pragma unroll
        for (int j = 0; j < 4; ++j) tm[j] = fmaxf(tm[j], __shfl_xor(tm[j], off, 16));
      float al[4];
#pragma unroll
      for (int j = 0; j < 4; ++j) {
        float nm = fmaxf(mrow[j], tm[j]);
        al[j] = __expf(mrow[j] - nm);
        mrow[j] = nm;
      }
#pragma unroll
      for (int d = 0; d < 8; ++d)
#pragma unroll
        for (int j = 0; j < 4; ++j) o[d][j] *= al[j];
#pragma unroll
      for (int j = 0; j < 4; ++j) lsum[j] *= al[j];
    }

    // ---- hoisted V tr16 batches 0,1,2 (latency hides under exp below) ----
    short4s tb[4][4];
#define TRISSUE(dblk, slot)                                                  \
    {                                                                        \
      const u16* vb = &sV[cur][(lk * 2) * 512 + (dblk) * 64 + ln * 4];       \
      tb[slot][0] = tr16(vb);                                                \
      tb[slot][1] = tr16(vb + 512);                                          \
      tb[slot][2] = tr16(vb + 4096);                                         \
      tb[slot][3] = tr16(vb + 4096 + 512);                                   \
    }
    TRISSUE(0, 0);
    TRISSUE(1, 1);
    TRISSUE(2, 2);

    // ---- P = exp(S - m): compiler bf16 cast; lsum from unrounded p ----
#pragma unroll
    for (int nc = 0; nc < 4; ++nc)
#pragma unroll
      for (int j = 0; j < 4; ++j) {
        float p = __expf(sf[nc][j] - mrow[j]);
        __hip_bfloat16 hb = __float2bfloat16(p);
        sP[w][(lk * 4 + j) * 72 + nc * 16 + ln] = *(u16*)&hb;
        lsum[j] += p;
      }

    short8 pa0 = *(const short8*)&sP[w][ln * 72 + lk * 8];
    short8 pa1 = *(const short8*)&sP[w][ln * 72 + 32 + lk * 8];
    asm volatile("s_waitcnt lgkmcnt(0)" ::: "memory");
    __builtin_amdgcn_sched_barrier(0);

    __builtin_amdgcn_s_setprio(1);
#pragma unroll
    for (int d = 0; d < 8; ++d) {
      if (d < 5) TRISSUE(d + 3, (d + 3) & 3);
      if (d < 5)       asm volatile("s_waitcnt lgkmcnt(12)" ::: "memory");
      else if (d == 5) asm volatile("s_waitcnt lgkmcnt(8)" ::: "memory");
      else if (d == 6) asm volatile("s_waitcnt lgkmcnt(4)" ::: "memory");
      else             asm volatile("s_waitcnt lgkmcnt(0)" ::: "memory");
      __builtin_amdgcn_sched_barrier(0);
      short8 vb0 = {tb[d & 3][0][0], tb[d & 3][0][1], tb[d & 3][0][2], tb[d & 3][0][3],
                    tb[d & 3][1][0], tb[d & 3][1][1], tb[d & 3][1][2], tb[d & 3][1][3]};
      short8 vb1 = {tb[d & 3][2][0], tb[d & 3][2][1], tb[d & 3][2][2], tb[d & 3][2][3],
                    tb[d & 3][3][0], tb[d & 3][3][1], tb[d & 3][3][2], tb[d & 3][3][3]};
      o[d] = MFMA(pa0, vb0, o[d]);
      o[d] = MFMA(pa1, vb1, o[d]);
    }
    __builtin_amdgcn_s_setprio(0);
#undef TRISSUE

    __syncthreads();
    cur ^= 1;
  }

#pragma unroll
  for (int off = 1; off < 16; off <<= 1)
#pragma unroll
    for (int j = 0; j < 4; ++j) lsum[j] += __shfl_xor(lsum[j], off, 16);
  float inv[4];
#pragma unroll
  for (int j = 0; j < 4; ++j) inv[j] = 1.f / lsum[j];
#pragma unroll
  for (int d = 0; d < 8; ++d)
#pragma unroll
    for (int j = 0; j < 4; ++j)
      out[(size_t)(m0 + w * 16 + lk * 4 + j) * 2048 + h * 128 + d * 16 + ln] =
          f2b(o[d][j] * inv[j]);
}

extern "C" void kernel_launch(void* const* d_in, const int* in_sizes, int n_in,
                              void* d_out, int out_size, void* d_ws, size_t ws_size,
                              hipStream_t stream) {
  const float* x  = (const float*)d_in[0];
  const float* wq = (const float*)d_in[1];
  const float* wk = (const float*)d_in[2];
  const float* wv = (const float*)d_in[3];
  const float* wo = (const float*)d_in[4];
  const float* fc = (const float*)d_in[5];
  const float* fs = (const float*)d_in[6];

  char* ws = (char*)d_ws;
  u16* xb   = (u16*)(ws);
  u16* wqkv = (u16*)(ws + 16777216);
  u16* wob  = (u16*)(ws + 41943040);
  u16* qkv  = (u16*)(ws + 50331648);
  u16* aout = (u16*)(ws + 100663296);

  cast_all<<<24576, 256, 0, stream>>>(x, wq, wk, wv, wo, xb, wqkv, wob);
  gemm_wide<0><<<256, 512, 0, stream>>>(xb, wqkv, qkv, 4096, 6144, 2048);
  rope_k<<<4096, 256, 0, stream>>>(qkv, fc, fs);
  attn_fwd<<<512, 512, 0, stream>>>(qkv, fc, fs, aout);
  gemm_big<2, 1><<<256, 512, 0, stream>>>(aout, wob, d_out, 4096, 2048, 2048);
}